// Round 2
// baseline (3805.988 us; speedup 1.0000x reference)
//
#include <hip/hip_runtime.h>
#include <stdint.h>

// Problem constants
#define B_   128
#define C_   512
#define P_   196
#define PP_  200     // padded P for bf16 image features
#define T_   32
#define V_   10403
#define E_   128
#define U_   256
#define KX_  896     // C+E+U : X row width in PAIRED u32 units (attn|emb|h)
#define K2_  1792    // doubled K for hi/lo split GEMM
#define NPAD_ 10496  // 82 * 128, padded N for the logits GEMM

typedef unsigned short u16;
typedef __attribute__((ext_vector_type(8))) short bf16x8;
typedef __attribute__((ext_vector_type(4))) float f32x4;

__device__ __forceinline__ float b2f(u16 u){
  union { unsigned int i; float f; } v; v.i = ((unsigned int)u) << 16; return v.f;
}
__device__ __forceinline__ u16 f2b(float f){
  union { float f; unsigned int i; } v; v.f = f;
  unsigned int r = (v.i + 0x7FFFu + ((v.i >> 16) & 1u)) >> 16;
  return (u16)r;
}
// duplicate one bf16 value into both halves of a u32 (K-doubled X element)
__device__ __forceinline__ unsigned int dup(float a){
  return (unsigned int)f2b(a) * 0x00010001u;
}
// hi/lo split of fp32 weight into two bf16 halves packed in one u32
__device__ __forceinline__ unsigned int hl(float w){
  u16 h = f2b(w);
  float lo = w - b2f(h);
  return (unsigned int)h | ((unsigned int)f2b(lo) << 16);
}

// ---------------- prep: mean over P + bf16 image features --------------
// thread = one (b,c) row: sum 196 f32, write mean + 200 bf16 (4 zero-pad)
__global__ void k_prep(const float* __restrict__ imf, float* __restrict__ mean,
                       u16* __restrict__ imb){
  int idx = blockIdx.x * 256 + threadIdx.x;          // b*C + c, 65536 total
  const float4* p4 = (const float4*)(imf + (size_t)idx * P_);
  u16* orow = imb + (size_t)idx * PP_;
  float s = 0.f;
  for (int i = 0; i < 49; ++i){
    float4 q = p4[i];
    s += q.x + q.y + q.z + q.w;
    ushort4 o;
    o.x = f2b(q.x); o.y = f2b(q.y); o.z = f2b(q.z); o.w = f2b(q.w);
    *((ushort4*)(orow + 4 * i)) = o;
  }
  ushort4 z; z.x = z.y = z.z = z.w = 0;
  *((ushort4*)(orow + 196)) = z;
  mean[idx] = s * (1.f / 196.f);
}

// ---------------- h0 = mean@W_h0^T + b_h0 ; c0 = mean@W_c0^T + b_c0 ----
__global__ void k_h0c0(const float* __restrict__ mean,
                       const float* __restrict__ Wh, const float* __restrict__ bh,
                       const float* __restrict__ Wc, const float* __restrict__ bc,
                       float* __restrict__ h0, float* __restrict__ c0,
                       unsigned int* __restrict__ h0b){
  int idx = blockIdx.x * 256 + threadIdx.x;          // b*512 + j
  int b = idx >> 9, j = idx & 511;
  int u = j & 255, isc = j >> 8;
  const float* wr = (isc ? Wc : Wh) + (size_t)u * C_;
  const float* m = mean + b * C_;
  float s = 0.f;
  for (int c = 0; c < C_; ++c) s += m[c] * wr[c];
  s += (isc ? bc : bh)[u];
  (isc ? c0 : h0)[b * U_ + u] = s;
  if (!isc) h0b[b * U_ + u] = dup(s);   // bf16 dup copy for gates t=0
}

// ---------------- gate weights: reorder + hi/lo K-doubled bf16 ---------
// Wg2 u32[1024][896]: col k order matches X (attn|emb|h); u32 = hi|lo
__global__ void k_wprep(const float* __restrict__ Wih, const float* __restrict__ bih,
                        const float* __restrict__ Whh, const float* __restrict__ bhh,
                        unsigned int* __restrict__ Wg2, float* __restrict__ bg){
  int idx = blockIdx.x * 256 + threadIdx.x;          // 1024*896
  int j = idx / 896, k = idx - j * 896;
  float w;
  if (k < 512)      w = Wih[(size_t)j * 640 + 128 + k];   // attn part
  else if (k < 640) w = Wih[(size_t)j * 640 + (k - 512)]; // emb part
  else              w = Whh[(size_t)j * 256 + (k - 640)]; // h part
  Wg2[(size_t)j * 896 + k] = hl(w);
  if (idx < 1024) bg[idx] = bih[idx] + bhh[idx];
}

// ---------------- fused qk + attention + X fill, one block per b -------
__global__ void __launch_bounds__(512) k_attn2(
    const u16* __restrict__ imb, const float* __restrict__ qsrc,
    const float* __restrict__ Wk, const int* __restrict__ cap,
    const float* __restrict__ emb, unsigned int* __restrict__ X,
    float* __restrict__ maps, int t)
{
  __shared__ __align__(16) float qs[U_];
  __shared__ __align__(16) float qk[C_];
  __shared__ __align__(16) float red[512];
  __shared__ __align__(16) float wl[PP_];
  int b = blockIdx.x, tid = threadIdx.x;
  if (tid < U_) qs[tid] = qsrc[b * U_ + tid];
  __syncthreads();
  // qk[c] = sum_u q[u] * Wkey[u][c]  (b_key is softmax-invariant)
  {
    float a = 0.f;
    for (int u = 0; u < U_; ++u) a += qs[u] * Wk[u * C_ + tid];
    qk[tid] = a;
  }
  __syncthreads();
  // scores: p = tid&255, half-c = tid>>8
  int p = tid & 255, hc = tid >> 8;
  float part = 0.f;
  if (p < P_){
    const u16* base = imb + (size_t)b * C_ * PP_ + p;
    int c0 = hc * 256;
    for (int c = c0; c < c0 + 256; ++c)
      part += qk[c] * b2f(base[(size_t)c * PP_]);
  }
  red[tid] = part;
  __syncthreads();
  float sval = -1e30f;
  if (tid < P_) sval = (red[tid] + red[tid + 256]) * 0.0625f;  // 1/sqrt(256)
  __syncthreads();
  if (tid < 256) red[tid] = sval;
  __syncthreads();
  for (int off = 128; off > 0; off >>= 1){
    if (tid < off) red[tid] = fmaxf(red[tid], red[tid + off]);
    __syncthreads();
  }
  float mx = red[0];
  __syncthreads();
  float e = (tid < P_) ? __expf(sval - mx) : 0.f;
  if (tid < 256) red[tid] = e;
  __syncthreads();
  for (int off = 128; off > 0; off >>= 1){
    if (tid < off) red[tid] += red[tid + off];
    __syncthreads();
  }
  float inv = 1.f / red[0];
  if (tid < PP_) wl[tid] = (tid < P_) ? e * inv : 0.f;
  if (tid < P_)  maps[(size_t)(b * T_ + t) * P_ + tid] = e * inv;
  __syncthreads();
  // weighted sum: c = tid (512 threads)
  size_t xrow = (size_t)(b * T_ + t) * KX_;
  {
    const u16* vrow = imb + ((size_t)b * C_ + tid) * PP_;
    float a = 0.f;
    for (int i = 0; i < 25; ++i){
      bf16x8 v8 = *((const bf16x8*)(vrow + i * 8));
      #pragma unroll
      for (int j = 0; j < 8; ++j) a += wl[i * 8 + j] * b2f((u16)v8[j]);
    }
    X[xrow + tid] = dup(a);
  }
  if (tid < E_){
    int ix = cap[b * T_ + t];
    X[xrow + C_ + tid] = dup(emb[(size_t)ix * E_ + tid]);
  }
}

// ---------------- gates GEMM (MFMA, K-doubled hi/lo W) + LSTM ----------
// grid 128 = 8 b-tiles(16) x 16 u-tiles(16); 4 waves, wave = gate index.
// A = X rows (dup bf16), B = Wg2 (hi/lo) -> ~fp32 weight precision.
__global__ void __launch_bounds__(256) k_gates2(
    const u16* __restrict__ Wg2, const float* __restrict__ bg,
    const u16* __restrict__ X16, const u16* __restrict__ h0b,
    float* __restrict__ c_st, float* __restrict__ hnew,
    unsigned int* __restrict__ X, int t)
{
  __shared__ __align__(16) u16 xg[16 * 64];
  __shared__ __align__(16) u16 wt[64 * 64];
  __shared__ __align__(16) float gl[4 * 16 * 16];
  int tid = threadIdx.x;
  int b0 = (blockIdx.x >> 4) * 16;
  int u0 = (blockIdx.x & 15) * 16;
  int lane = tid & 63, wv = tid >> 6;
  int quad = lane >> 4, l15 = lane & 15;
  f32x4 acc = {0.f, 0.f, 0.f, 0.f};
  int xr = tid >> 3, xseg = tid & 7;           // xg chunk (tid<128)
  for (int kc = 0; kc < 28; ++kc){
    int kd = kc * 64;                          // doubled-k offset
    if (tid < 128){                            // waves 0,1: stage xg[16][64]
      const u16* src;
      if (kc < 20)      src = X16 + ((size_t)((b0 + xr) * T_ + t)) * K2_ + kd + xseg * 8;
      else if (t > 0)   src = X16 + ((size_t)((b0 + xr) * T_ + t - 1)) * K2_ + kd + xseg * 8;
      else              src = h0b + (b0 + xr) * 512 + (kd - 1280) + xseg * 8;
      __builtin_amdgcn_global_load_lds(src, xg + tid * 8, 16, 0, 0);
    }
    {                                          // all: stage wt[64][64]
      int jl0 = tid >> 3, sg0 = tid & 7;
      int j0 = ((jl0 >> 4) << 8) + u0 + (jl0 & 15);
      __builtin_amdgcn_global_load_lds(Wg2 + (size_t)j0 * K2_ + kd + sg0 * 8,
                                       wt + tid * 8, 16, 0, 0);
      int ci1 = tid + 256, jl1 = ci1 >> 3, sg1 = ci1 & 7;
      int j1 = ((jl1 >> 4) << 8) + u0 + (jl1 & 15);
      __builtin_amdgcn_global_load_lds(Wg2 + (size_t)j1 * K2_ + kd + sg1 * 8,
                                       wt + ci1 * 8, 16, 0, 0);
    }
    __syncthreads();
    bf16x8 a0 = *((const bf16x8*)(xg + l15 * 64 + quad * 8));
    bf16x8 a1 = *((const bf16x8*)(xg + l15 * 64 + 32 + quad * 8));
    bf16x8 b0v = *((const bf16x8*)(wt + (wv * 16 + l15) * 64 + quad * 8));
    bf16x8 b1v = *((const bf16x8*)(wt + (wv * 16 + l15) * 64 + 32 + quad * 8));
    acc = __builtin_amdgcn_mfma_f32_16x16x32_bf16(a0, b0v, acc, 0, 0, 0);
    acc = __builtin_amdgcn_mfma_f32_16x16x32_bf16(a1, b1v, acc, 0, 0, 0);
    __syncthreads();
  }
  #pragma unroll
  for (int r = 0; r < 4; ++r)
    gl[(wv << 8) + ((quad * 4 + r) << 4) + l15] = acc[r];
  __syncthreads();
  {
    int br = tid >> 4, ur = tid & 15;
    int b = b0 + br, u = u0 + ur;
    float i_g = gl[(0 << 8) + (br << 4) + ur] + bg[u];
    float f_g = gl[(1 << 8) + (br << 4) + ur] + bg[256 + u];
    float g_g = gl[(2 << 8) + (br << 4) + ur] + bg[512 + u];
    float o_g = gl[(3 << 8) + (br << 4) + ur] + bg[768 + u];
    float cold = c_st[b * U_ + u];
    float si = 1.f / (1.f + __expf(-i_g));
    float sf = 1.f / (1.f + __expf(-f_g));
    float so = 1.f / (1.f + __expf(-o_g));
    float cn = sf * cold + si * tanhf(g_g);
    float hn = so * tanhf(cn);
    c_st[b * U_ + u] = cn;
    hnew[b * U_ + u] = hn;
    X[(size_t)(b * T_ + t) * KX_ + 640 + u] = dup(hn);
  }
}

// ---------------- W_out -> hi/lo bf16 pairs, zero-padded to NPAD_ ------
__global__ void k_wsplit(const float* __restrict__ Wout,
                         unsigned int* __restrict__ W2){
  int idx = blockIdx.x * 256 + threadIdx.x;        // NPAD_*224 = 2,351,104
  int v = idx / 224, kq = idx - v * 224;
  uint4 o;
  if (v < V_){
    float4 w = ((const float4*)(Wout + (size_t)v * KX_))[kq];
    o.x = hl(w.x); o.y = hl(w.y); o.z = hl(w.z); o.w = hl(w.w);
  } else {
    o.x = o.y = o.z = o.w = 0u;
  }
  ((uint4*)(W2 + (size_t)v * KX_))[kq] = o;
}

// ---------------- logits GEMM: MFMA, m97 structure + XCD swizzle -------
// C[4096, NPAD_] = A2[4096, K2_] * W2[NPAD_, K2_]^T  (bf16, K doubled)
__global__ void __launch_bounds__(256) k_logits(
    const u16* __restrict__ A2, const u16* __restrict__ W2,
    const float* __restrict__ bout, float* __restrict__ out)
{
  __shared__ __align__(16) u16 As[128 * 32];
  __shared__ __align__(16) u16 Bs[128 * 32];
  int tid = threadIdx.x;
  // XCD-aware bijective swizzle: nwg = 82*32 = 2624 = 8 * 328
  int flat = blockIdx.y * 82 + blockIdx.x;
  int swz = (flat & 7) * 328 + (flat >> 3);
  int n0 = (swz % 82) * 128;
  int m0 = (swz / 82) * 128;
  int lane = tid & 63, wv = tid >> 6;
  int wm = wv >> 1, wn = wv & 1;
  int quad = lane >> 4, l15 = lane & 15;

  f32x4 acc[4][4];
  #pragma unroll
  for (int i = 0; i < 4; ++i)
    #pragma unroll
    for (int j = 0; j < 4; ++j)
      acc[i][j] = (f32x4){0.f, 0.f, 0.f, 0.f};

  int rsub = tid >> 2, seg = tid & 3;
  const u16* ga0 = A2 + (size_t)(m0 + rsub)      * K2_ + seg * 8;
  const u16* ga1 = A2 + (size_t)(m0 + 64 + rsub) * K2_ + seg * 8;
  const u16* gb0 = W2 + (size_t)(n0 + rsub)      * K2_ + seg * 8;
  const u16* gb1 = W2 + (size_t)(n0 + 64 + rsub) * K2_ + seg * 8;
  u16* lA0 = As + tid * 8;
  u16* lA1 = As + (256 + tid) * 8;
  u16* lB0 = Bs + tid * 8;
  u16* lB1 = Bs + (256 + tid) * 8;

  const u16* arow0 = As + (wm * 64 + l15) * 32 + quad * 8;
  const u16* brow0 = Bs + (wn * 64 + l15) * 32 + quad * 8;

  for (int kc = 0; kc < 56; ++kc){
    __builtin_amdgcn_global_load_lds(ga0, lA0, 16, 0, 0);
    __builtin_amdgcn_global_load_lds(ga1, lA1, 16, 0, 0);
    __builtin_amdgcn_global_load_lds(gb0, lB0, 16, 0, 0);
    __builtin_amdgcn_global_load_lds(gb1, lB1, 16, 0, 0);
    ga0 += 32; ga1 += 32; gb0 += 32; gb1 += 32;
    __syncthreads();
    bf16x8 a[4], b[4];
    #pragma unroll
    for (int i = 0; i < 4; ++i)
      a[i] = *((const bf16x8*)(arow0 + i * 16 * 32));
    #pragma unroll
    for (int j = 0; j < 4; ++j)
      b[j] = *((const bf16x8*)(brow0 + j * 16 * 32));
    #pragma unroll
    for (int i = 0; i < 4; ++i)
      #pragma unroll
      for (int j = 0; j < 4; ++j)
        acc[i][j] = __builtin_amdgcn_mfma_f32_16x16x32_bf16(a[i], b[j], acc[i][j], 0, 0, 0);
    __syncthreads();
  }

  int orow = m0 + wm * 64 + quad * 4;
  #pragma unroll
  for (int j = 0; j < 4; ++j){
    int v = n0 + wn * 64 + j * 16 + l15;
    if (v < V_){
      float bo = bout[v];
      #pragma unroll
      for (int i = 0; i < 4; ++i){
        #pragma unroll
        for (int r = 0; r < 4; ++r)
          out[(size_t)(orow + i * 16 + r) * V_ + v] = acc[i][j][r] + bo;
      }
    }
  }
}

extern "C" void kernel_launch(void* const* d_in, const int* in_sizes, int n_in,
                              void* d_out, int out_size, void* d_ws, size_t ws_size,
                              hipStream_t stream)
{
  const float* imf  = (const float*)d_in[0];
  const int*   cap  = (const int*)d_in[1];
  const float* Wh0  = (const float*)d_in[2];
  const float* bh0  = (const float*)d_in[3];
  const float* Wc0  = (const float*)d_in[4];
  const float* bc0  = (const float*)d_in[5];
  const float* Wkey = (const float*)d_in[6];
  // d_in[7] = b_key: softmax-invariant (constant shift per b) -> unused
  const float* emb  = (const float*)d_in[8];
  const float* Wih  = (const float*)d_in[9];
  const float* bih  = (const float*)d_in[10];
  const float* Whh  = (const float*)d_in[11];
  const float* bhh  = (const float*)d_in[12];
  const float* Wout = (const float*)d_in[13];
  const float* bout = (const float*)d_in[14];

  // workspace layout (~83 MB)
  float* mean  = (float*)d_ws;                        // 65536 f32
  float* hbuf0 = mean  + 65536;                       // 32768
  float* hbuf1 = hbuf0 + 32768;                       // 32768
  float* cbuf  = hbuf1 + 32768;                       // 32768
  float* bg    = cbuf  + 32768;                       // 1024
  unsigned int* h0b = (unsigned int*)(bg + 1024);     // 128*256 u32 (dup bf16 h0)
  unsigned int* X   = h0b + 32768;                    // 4096*896 u32 (dup bf16)
  unsigned int* W2  = X + (size_t)4096 * KX_;         // 10496*896 u32 (hi|lo)
  unsigned int* Wg2 = W2 + (size_t)NPAD_ * KX_;       // 1024*896 u32 (hi|lo)
  u16* imb = (u16*)(Wg2 + (size_t)1024 * KX_);        // 128*512*200 bf16

  float* out  = (float*)d_out;
  float* maps = out + (size_t)B_ * T_ * V_;

  k_wsplit<<<9184, 256, 0, stream>>>(Wout, W2);
  k_wprep<<<3584, 256, 0, stream>>>(Wih, bih, Whh, bhh, Wg2, bg);
  k_prep<<<256, 256, 0, stream>>>(imf, mean, imb);
  k_h0c0<<<256, 256, 0, stream>>>(mean, Wh0, bh0, Wc0, bc0, hbuf0, cbuf, h0b);
  for (int t = 0; t < T_; ++t){
    const float* q  = (t == 0) ? cbuf : ((t & 1) ? hbuf1 : hbuf0);
    float*       hn = (t & 1) ? hbuf0 : hbuf1;
    k_attn2<<<128, 512, 0, stream>>>(imb, q, Wkey, cap, emb, X, maps, t);
    k_gates2<<<128, 256, 0, stream>>>((const u16*)Wg2, bg, (const u16*)X,
                                      (const u16*)h0b, cbuf, hn, X, t);
  }
  k_logits<<<dim3(82, 32), 256, 0, stream>>>((const u16*)X, (const u16*)W2,
                                             bout, out);
}

// Round 3
// 2907.467 us; speedup vs baseline: 1.3090x; 1.3090x over previous
//
#include <hip/hip_runtime.h>
#include <stdint.h>

// Problem constants
#define B_   128
#define C_   512
#define P_   196
#define PP2_ 208     // padded P for keysT rows
#define T_   32
#define V_   10403
#define E_   128
#define U_   256
#define KX_  896     // C+E+U : X row width in PAIRED u32 units (attn|emb|h)
#define K2_  1792    // doubled K for hi/lo split GEMM
#define NPAD_ 10496  // 82 * 128, padded N for the logits GEMM

typedef unsigned short u16;
typedef __attribute__((ext_vector_type(8))) short bf16x8;
typedef __attribute__((ext_vector_type(4))) float f32x4;

__device__ __forceinline__ float b2f(u16 u){
  union { unsigned int i; float f; } v; v.i = ((unsigned int)u) << 16; return v.f;
}
__device__ __forceinline__ u16 f2b(float f){
  union { float f; unsigned int i; } v; v.f = f;
  unsigned int r = (v.i + 0x7FFFu + ((v.i >> 16) & 1u)) >> 16;
  return (u16)r;
}
__device__ __forceinline__ unsigned int pk2(float a, float b){
  return (unsigned int)f2b(a) | ((unsigned int)f2b(b) << 16);
}
// duplicate one bf16 value into both halves of a u32 (K-doubled X element)
__device__ __forceinline__ unsigned int dup(float a){
  return (unsigned int)f2b(a) * 0x00010001u;
}
// hi/lo split of fp32 weight into two bf16 halves packed in one u32
__device__ __forceinline__ unsigned int hl(float w){
  u16 h = f2b(w);
  float lo = w - b2f(h);
  return (unsigned int)h | ((unsigned int)f2b(lo) << 16);
}

// ---------------- mean over P (image_features [B,C,P] fp32) ------------
__global__ void k_mean(const float* __restrict__ imf, float* __restrict__ mean){
  int idx = blockIdx.x * 256 + threadIdx.x;          // b*C + c, 65536 total
  const float4* p4 = (const float4*)(imf + (size_t)idx * P_);
  float s = 0.f;
  for (int i = 0; i < 49; ++i){
    float4 q = p4[i];
    s += q.x + q.y + q.z + q.w;
  }
  mean[idx] = s * (1.f / 196.f);
}

// ---------------- h0 = mean@W_h0^T + b_h0 ; c0 = mean@W_c0^T + b_c0 ----
__global__ void k_h0c0(const float* __restrict__ mean,
                       const float* __restrict__ Wh, const float* __restrict__ bh,
                       const float* __restrict__ Wc, const float* __restrict__ bc,
                       float* __restrict__ h0, float* __restrict__ c0){
  int idx = blockIdx.x * 256 + threadIdx.x;          // b*512 + j
  int b = idx >> 9, j = idx & 511;
  int u = j & 255, isc = j >> 8;
  const float* wr = (isc ? Wc : Wh) + (size_t)u * C_;
  const float* m = mean + b * C_;
  float s = 0.f;
  for (int c = 0; c < C_; ++c) s += m[c] * wr[c];
  s += (isc ? bc : bh)[u];
  (isc ? c0 : h0)[b * U_ + u] = s;
}

// ---------------- Wkey f32 -> bf16 -----------------------------------
__global__ void k_wkeyb(const float* __restrict__ Wk, u16* __restrict__ WkB){
  int idx = blockIdx.x * 256 + threadIdx.x;          // 256*512 = 131072
  WkB[idx] = f2b(Wk[idx]);
}

// ---------------- keysT[b,u,p] = sum_c Wkey[u,c] * imf[b,c,p] ----------
// one-time MFMA GEMM, bf16 out. grid (13 p-tiles x 128 b), 4 waves.
// wave wv covers u in [wv*64, wv*64+64) as 4 m-tiles of 16.
__global__ void __launch_bounds__(256) k_keys(
    const float* __restrict__ imf, const u16* __restrict__ WkeyB,
    u16* __restrict__ keysT)
{
  __shared__ __align__(16) u16 Bs[16 * 40];   // [p][k], stride 40 breaks conflicts
  int tid = threadIdx.x;
  int p0 = blockIdx.x * 16;                   // 0..192
  int b  = blockIdx.y;
  int lane = tid & 63, wv = tid >> 6;
  int quad = lane >> 4, l15 = lane & 15;
  f32x4 acc[4];
  #pragma unroll
  for (int m = 0; m < 4; ++m) acc[m] = (f32x4){0.f, 0.f, 0.f, 0.f};
  for (int kc = 0; kc < 16; ++kc){
    int k0 = kc * 32;
    #pragma unroll
    for (int e = tid; e < 512; e += 256){
      int kk = e >> 4, pp = e & 15;
      int p = p0 + pp;
      float v = (p < P_) ? imf[((size_t)b * C_ + (k0 + kk)) * P_ + p] : 0.f;
      Bs[pp * 40 + kk] = f2b(v);
    }
    __syncthreads();
    bf16x8 bfrag = *((const bf16x8*)(Bs + l15 * 40 + quad * 8));
    #pragma unroll
    for (int m = 0; m < 4; ++m){
      int u = wv * 64 + m * 16 + l15;
      bf16x8 afrag = *((const bf16x8*)(WkeyB + (size_t)u * C_ + k0 + quad * 8));
      acc[m] = __builtin_amdgcn_mfma_f32_16x16x32_bf16(afrag, bfrag, acc[m], 0, 0, 0);
    }
    __syncthreads();
  }
  #pragma unroll
  for (int m = 0; m < 4; ++m){
    #pragma unroll
    for (int r = 0; r < 4; ++r){
      int u = wv * 64 + m * 16 + quad * 4 + r;
      keysT[((size_t)b * U_ + u) * PP2_ + p0 + l15] = f2b(acc[m][r]);
    }
  }
}

// ---------------- attention: scores(keysT) -> softmax -> attn; fill X --
__global__ void __launch_bounds__(256) k_attn3(
    const float* __restrict__ imf, const u16* __restrict__ keysT,
    const float* __restrict__ qsrc, const int* __restrict__ cap,
    const float* __restrict__ emb, float* __restrict__ attn_ws,
    unsigned int* __restrict__ X, float* __restrict__ maps, int t)
{
  __shared__ __align__(16) float qs[U_];
  __shared__ __align__(16) float red[256];
  __shared__ __align__(16) float wl[P_];
  int b = blockIdx.x, tid = threadIdx.x;
  qs[tid] = qsrc[b * U_ + tid];               // blockDim == U_ == 256
  __syncthreads();
  float s = -1e30f;
  if (tid < P_){
    const u16* kp = keysT + (size_t)b * (U_ * PP2_) + tid;
    float acc = 0.f;
    #pragma unroll 4
    for (int u = 0; u < U_; ++u) acc += qs[u] * b2f(kp[u * PP2_]);
    s = acc * 0.0625f;   // 1/sqrt(256)
  }
  red[tid] = s; __syncthreads();
  for (int off = 128; off > 0; off >>= 1){
    if (tid < off) red[tid] = fmaxf(red[tid], red[tid + off]);
    __syncthreads();
  }
  float mx = red[0]; __syncthreads();
  float e = (tid < P_) ? __expf(s - mx) : 0.f;
  red[tid] = e; __syncthreads();
  for (int off = 128; off > 0; off >>= 1){
    if (tid < off) red[tid] += red[tid + off];
    __syncthreads();
  }
  float inv = 1.f / red[0];
  if (tid < P_){
    float w = e * inv;
    wl[tid] = w;
    maps[(size_t)(b * T_ + t) * P_ + tid] = w;
  }
  __syncthreads();
  size_t xrow = (size_t)(b * T_ + t) * KX_;
  for (int c = tid; c < C_; c += 256){
    const float4* p4 = (const float4*)(imf + ((size_t)b * C_ + c) * P_);
    float a = 0.f;
    for (int i = 0; i < 49; ++i){
      float4 q4 = p4[i];
      a += wl[4*i]   * q4.x + wl[4*i+1] * q4.y
         + wl[4*i+2] * q4.z + wl[4*i+3] * q4.w;
    }
    attn_ws[b * C_ + c] = a;
    X[xrow + c] = dup(a);
  }
  if (tid < E_){
    int ix = cap[b * T_ + t];
    X[xrow + C_ + tid] = dup(emb[(size_t)ix * E_ + tid]);
  }
}

// ---------------- gates GEMM (MFMA) + LSTM pointwise -------------------
// grid 128 = 8 b-tiles(16) x 16 u-tiles(16); 4 waves, wave = gate index.
__global__ void __launch_bounds__(256) k_gates(
    const float* __restrict__ Wih, const float* __restrict__ bih,
    const float* __restrict__ Whh, const float* __restrict__ bhh,
    const int* __restrict__ cap, const float* __restrict__ emb,
    const float* __restrict__ attn_ws, const float* __restrict__ hprev,
    float* __restrict__ c_st, float* __restrict__ hnew,
    unsigned int* __restrict__ X, int t)
{
  __shared__ __align__(16) u16 xg[16 * 32];
  __shared__ __align__(16) u16 wt[64 * 32];
  __shared__ __align__(16) float gl[4 * 16 * 16];
  __shared__ int ixl[16];
  int tid = threadIdx.x;
  int b0 = (blockIdx.x >> 4) * 16;
  int u0 = (blockIdx.x & 15) * 16;
  if (tid < 16) ixl[tid] = cap[(b0 + tid) * T_ + t];
  __syncthreads();
  int lane = tid & 63, wv = tid >> 6;
  int quad = lane >> 4, l15 = lane & 15;
  f32x4 acc = {0.f, 0.f, 0.f, 0.f};
  for (int kc = 0; kc < 28; ++kc){
    int k0 = kc * 32;
    // stage xg[16][32]: k<128 emb, 128..639 attn, 640..895 h  (f32 -> bf16)
    for (int e2 = tid; e2 < 512; e2 += 256){
      int r = e2 >> 5, kk = e2 & 31, k = k0 + kk;
      float v;
      if (k < 128)      v = emb[(size_t)ixl[r] * E_ + k];
      else if (k < 640) v = attn_ws[(b0 + r) * C_ + (k - 128)];
      else              v = hprev[(b0 + r) * U_ + (k - 640)];
      xg[e2] = f2b(v);
    }
    // stage wt[64][32]: rows j = g*256 + u0 + r (g=jl>>4, r=jl&15), f32->bf16
    {
      int jl = tid >> 2, seg = tid & 3;
      int g = jl >> 4, r = jl & 15;
      int j = g * 256 + u0 + r;
      const float* src = (kc < 20)
          ? (Wih + (size_t)j * 640 + k0 + seg * 8)
          : (Whh + (size_t)j * 256 + (k0 - 640) + seg * 8);
      float4 lo = ((const float4*)src)[0];
      float4 hi = ((const float4*)src)[1];
      uint4 o;
      o.x = pk2(lo.x, lo.y); o.y = pk2(lo.z, lo.w);
      o.z = pk2(hi.x, hi.y); o.w = pk2(hi.z, hi.w);
      *((uint4*)(wt + jl * 32 + seg * 8)) = o;
    }
    __syncthreads();
    bf16x8 af  = *((const bf16x8*)(xg + l15 * 32 + quad * 8));
    bf16x8 bfv = *((const bf16x8*)(wt + (wv * 16 + l15) * 32 + quad * 8));
    acc = __builtin_amdgcn_mfma_f32_16x16x32_bf16(af, bfv, acc, 0, 0, 0);
    __syncthreads();
  }
  // D: row m = quad*4+reg (b), col n = l15 (u); wave wv = gate
  #pragma unroll
  for (int r = 0; r < 4; ++r)
    gl[(wv << 8) + ((quad * 4 + r) << 4) + l15] = acc[r];
  __syncthreads();
  {
    int br = tid >> 4, ur = tid & 15;
    int b = b0 + br, u = u0 + ur;
    float i_g = gl[(0 << 8) + (br << 4) + ur] + bih[u]       + bhh[u];
    float f_g = gl[(1 << 8) + (br << 4) + ur] + bih[256 + u] + bhh[256 + u];
    float g_g = gl[(2 << 8) + (br << 4) + ur] + bih[512 + u] + bhh[512 + u];
    float o_g = gl[(3 << 8) + (br << 4) + ur] + bih[768 + u] + bhh[768 + u];
    float cold = c_st[b * U_ + u];
    float si = 1.f / (1.f + __expf(-i_g));
    float sf = 1.f / (1.f + __expf(-f_g));
    float so = 1.f / (1.f + __expf(-o_g));
    float cn = sf * cold + si * tanhf(g_g);
    float hn = so * tanhf(cn);
    c_st[b * U_ + u] = cn;
    hnew[b * U_ + u] = hn;
    X[(size_t)(b * T_ + t) * KX_ + 640 + u] = dup(hn);
  }
}

// ---------------- W_out -> hi/lo bf16 pairs, zero-padded to NPAD_ ------
__global__ void k_wsplit(const float* __restrict__ Wout,
                         unsigned int* __restrict__ W2){
  int idx = blockIdx.x * 256 + threadIdx.x;        // NPAD_*224 = 2,351,104
  int v = idx / 224, kq = idx - v * 224;
  uint4 o;
  if (v < V_){
    float4 w = ((const float4*)(Wout + (size_t)v * KX_))[kq];
    o.x = hl(w.x); o.y = hl(w.y); o.z = hl(w.z); o.w = hl(w.w);
  } else {
    o.x = o.y = o.z = o.w = 0u;
  }
  ((uint4*)(W2 + (size_t)v * KX_))[kq] = o;
}

// ---------------- logits GEMM: MFMA, m97 structure ---------------------
// C[4096, NPAD_] = A2[4096, K2_] * W2[NPAD_, K2_]^T  (bf16, K doubled)
__global__ void __launch_bounds__(256) k_logits(
    const u16* __restrict__ A2, const u16* __restrict__ W2,
    const float* __restrict__ bout, float* __restrict__ out)
{
  __shared__ __align__(16) u16 As[128 * 32];
  __shared__ __align__(16) u16 Bs[128 * 32];
  int tid = threadIdx.x;
  int n0 = blockIdx.x * 128;
  int m0 = blockIdx.y * 128;
  int lane = tid & 63, wv = tid >> 6;
  int wm = wv >> 1, wn = wv & 1;
  int quad = lane >> 4, l15 = lane & 15;

  f32x4 acc[4][4];
  #pragma unroll
  for (int i = 0; i < 4; ++i)
    #pragma unroll
    for (int j = 0; j < 4; ++j)
      acc[i][j] = (f32x4){0.f, 0.f, 0.f, 0.f};

  int rsub = tid >> 2, seg = tid & 3;
  const u16* ga0 = A2 + (size_t)(m0 + rsub)      * K2_ + seg * 8;
  const u16* ga1 = A2 + (size_t)(m0 + 64 + rsub) * K2_ + seg * 8;
  const u16* gb0 = W2 + (size_t)(n0 + rsub)      * K2_ + seg * 8;
  const u16* gb1 = W2 + (size_t)(n0 + 64 + rsub) * K2_ + seg * 8;
  u16* lA0 = As + tid * 8;
  u16* lA1 = As + (256 + tid) * 8;
  u16* lB0 = Bs + tid * 8;
  u16* lB1 = Bs + (256 + tid) * 8;

  const u16* arow0 = As + (wm * 64 + l15) * 32 + quad * 8;
  const u16* brow0 = Bs + (wn * 64 + l15) * 32 + quad * 8;

  for (int kc = 0; kc < 56; ++kc){
    __builtin_amdgcn_global_load_lds(ga0, lA0, 16, 0, 0);
    __builtin_amdgcn_global_load_lds(ga1, lA1, 16, 0, 0);
    __builtin_amdgcn_global_load_lds(gb0, lB0, 16, 0, 0);
    __builtin_amdgcn_global_load_lds(gb1, lB1, 16, 0, 0);
    ga0 += 32; ga1 += 32; gb0 += 32; gb1 += 32;
    __syncthreads();
    bf16x8 a[4], b[4];
    #pragma unroll
    for (int i = 0; i < 4; ++i)
      a[i] = *((const bf16x8*)(arow0 + i * 16 * 32));
    #pragma unroll
    for (int j = 0; j < 4; ++j)
      b[j] = *((const bf16x8*)(brow0 + j * 16 * 32));
    #pragma unroll
    for (int i = 0; i < 4; ++i)
      #pragma unroll
      for (int j = 0; j < 4; ++j)
        acc[i][j] = __builtin_amdgcn_mfma_f32_16x16x32_bf16(a[i], b[j], acc[i][j], 0, 0, 0);
    __syncthreads();
  }

  int orow = m0 + wm * 64 + quad * 4;
  #pragma unroll
  for (int j = 0; j < 4; ++j){
    int v = n0 + wn * 64 + j * 16 + l15;
    if (v < V_){
      float bo = bout[v];
      #pragma unroll
      for (int i = 0; i < 4; ++i){
        #pragma unroll
        for (int r = 0; r < 4; ++r)
          out[(size_t)(orow + i * 16 + r) * V_ + v] = acc[i][j][r] + bo;
      }
    }
  }
}

extern "C" void kernel_launch(void* const* d_in, const int* in_sizes, int n_in,
                              void* d_out, int out_size, void* d_ws, size_t ws_size,
                              hipStream_t stream)
{
  const float* imf  = (const float*)d_in[0];
  const int*   cap  = (const int*)d_in[1];
  const float* Wh0  = (const float*)d_in[2];
  const float* bh0  = (const float*)d_in[3];
  const float* Wc0  = (const float*)d_in[4];
  const float* bc0  = (const float*)d_in[5];
  const float* Wkey = (const float*)d_in[6];
  // d_in[7] = b_key: softmax-invariant (constant shift per b) -> unused
  const float* emb  = (const float*)d_in[8];
  const float* Wih  = (const float*)d_in[9];
  const float* bih  = (const float*)d_in[10];
  const float* Whh  = (const float*)d_in[11];
  const float* bhh  = (const float*)d_in[12];
  const float* Wout = (const float*)d_in[13];
  const float* bout = (const float*)d_in[14];

  // workspace layout (~67 MB)
  float* mean  = (float*)d_ws;                        // 65536 f32
  float* hbuf0 = mean  + 65536;                       // 32768
  float* hbuf1 = hbuf0 + 32768;                       // 32768
  float* cbuf  = hbuf1 + 32768;                       // 32768
  float* attn  = cbuf  + 32768;                       // 65536
  unsigned int* X  = (unsigned int*)(attn + 65536);   // 4096*896 u32 (dup bf16)
  unsigned int* W2 = X + (size_t)4096 * KX_;          // 10496*896 u32 (hi|lo)
  u16* WkeyB = (u16*)(W2 + (size_t)NPAD_ * KX_);      // 256*512 bf16
  u16* keysT = WkeyB + 131072;                        // 128*256*208 bf16

  float* out  = (float*)d_out;
  float* maps = out + (size_t)B_ * T_ * V_;

  k_wsplit<<<9184, 256, 0, stream>>>(Wout, W2);
  k_wkeyb<<<512, 256, 0, stream>>>(Wkey, WkeyB);
  k_mean<<<256, 256, 0, stream>>>(imf, mean);
  k_keys<<<dim3(13, 128), 256, 0, stream>>>(imf, WkeyB, keysT);
  k_h0c0<<<256, 256, 0, stream>>>(mean, Wh0, bh0, Wc0, bc0, hbuf0, cbuf);
  for (int t = 0; t < T_; ++t){
    const float* q  = (t == 0) ? cbuf : ((t & 1) ? hbuf1 : hbuf0);
    const float* hp = (t & 1) ? hbuf1 : hbuf0;
    float*       hn = (t & 1) ? hbuf0 : hbuf1;
    k_attn3<<<128, 256, 0, stream>>>(imf, keysT, q, cap, emb, attn, X, maps, t);
    k_gates<<<128, 256, 0, stream>>>(Wih, bih, Whh, bhh, cap, emb, attn,
                                     hp, cbuf, hn, X, t);
  }
  k_logits<<<dim3(82, 32), 256, 0, stream>>>((const u16*)X, (const u16*)W2,
                                             bout, out);
}

// Round 4
// 2231.008 us; speedup vs baseline: 1.7059x; 1.3032x over previous
//
#include <hip/hip_runtime.h>
#include <stdint.h>

// Problem constants
#define B_   128
#define C_   512
#define P_   196
#define PP_  200     // padded P for bf16 image features rows
#define T_   32
#define V_   10403
#define E_   128
#define U_   256
#define KX_  896     // C+E+U : X row width in PAIRED u32 units (attn|emb|h)
#define K2_  1792    // doubled K for hi/lo split GEMM
#define NPAD_ 10496  // 82 * 128, padded N for the logits GEMM

typedef unsigned short u16;
typedef __attribute__((ext_vector_type(8))) short bf16x8;
typedef __attribute__((ext_vector_type(4))) float f32x4;

__device__ __forceinline__ float b2f(u16 u){
  union { unsigned int i; float f; } v; v.i = ((unsigned int)u) << 16; return v.f;
}
__device__ __forceinline__ u16 f2b(float f){
  union { float f; unsigned int i; } v; v.f = f;
  unsigned int r = (v.i + 0x7FFFu + ((v.i >> 16) & 1u)) >> 16;
  return (u16)r;
}
__device__ __forceinline__ unsigned int pk2(float a, float b){
  return (unsigned int)f2b(a) | ((unsigned int)f2b(b) << 16);
}
// duplicate one bf16 value into both halves of a u32 (K-doubled X element)
__device__ __forceinline__ unsigned int dup(float a){
  return (unsigned int)f2b(a) * 0x00010001u;
}
// hi/lo split of fp32 weight into two bf16 halves packed in one u32
__device__ __forceinline__ unsigned int hl(float w){
  u16 h = f2b(w);
  float lo = w - b2f(h);
  return (unsigned int)h | ((unsigned int)f2b(lo) << 16);
}

// ------------- prep: mean over P + bf16 image features [b][c][200] -----
__global__ void k_prep(const float* __restrict__ imf, float* __restrict__ mean,
                       u16* __restrict__ imb){
  int idx = blockIdx.x * 256 + threadIdx.x;          // b*C + c, 65536 total
  const float4* p4 = (const float4*)(imf + (size_t)idx * P_);
  u16* orow = imb + (size_t)idx * PP_;
  float s = 0.f;
  for (int i = 0; i < 49; ++i){
    float4 q = p4[i];
    s += q.x + q.y + q.z + q.w;
    ushort4 o;
    o.x = f2b(q.x); o.y = f2b(q.y); o.z = f2b(q.z); o.w = f2b(q.w);
    *((ushort4*)(orow + 4 * i)) = o;
  }
  ushort4 z; z.x = z.y = z.z = z.w = 0;
  *((ushort4*)(orow + 196)) = z;
  mean[idx] = s * (1.f / 196.f);
}

// ---------------- h0 = mean@W_h0^T + b_h0 ; c0 = mean@W_c0^T + b_c0 ----
__global__ void k_h0c0(const float* __restrict__ mean,
                       const float* __restrict__ Wh, const float* __restrict__ bh,
                       const float* __restrict__ Wc, const float* __restrict__ bc,
                       float* __restrict__ h0, float* __restrict__ c0){
  int idx = blockIdx.x * 256 + threadIdx.x;          // b*512 + j
  int b = idx >> 9, j = idx & 511;
  int u = j & 255, isc = j >> 8;
  const float* wr = (isc ? Wc : Wh) + (size_t)u * C_;
  const float* m = mean + b * C_;
  float s = 0.f;
  for (int c = 0; c < C_; ++c) s += m[c] * wr[c];
  s += (isc ? bc : bh)[u];
  (isc ? c0 : h0)[b * U_ + u] = s;
}

// ---------------- Wkey f32 -> bf16 -----------------------------------
__global__ void k_wkeyb(const float* __restrict__ Wk, u16* __restrict__ WkB){
  int idx = blockIdx.x * 256 + threadIdx.x;          // 256*512 = 131072
  WkB[idx] = f2b(Wk[idx]);
}

// ---------------- keysT[b,p,u] = sum_c Wkey[u,c] * imf[b,c,p] ----------
// one-time MFMA GEMM, bf16 out, u-contiguous rows. grid (13 p-tiles x 128 b).
// wave wv covers u in [wv*64, wv*64+64) as 4 m-tiles of 16.
__global__ void __launch_bounds__(256) k_keys(
    const float* __restrict__ imf, const u16* __restrict__ WkeyB,
    u16* __restrict__ keysT)
{
  __shared__ __align__(16) u16 Bs[16 * 40];   // [p][k], stride 40 breaks conflicts
  int tid = threadIdx.x;
  int p0 = blockIdx.x * 16;                   // 0..192
  int b  = blockIdx.y;
  int lane = tid & 63, wv = tid >> 6;
  int quad = lane >> 4, l15 = lane & 15;
  f32x4 acc[4];
  #pragma unroll
  for (int m = 0; m < 4; ++m) acc[m] = (f32x4){0.f, 0.f, 0.f, 0.f};
  for (int kc = 0; kc < 16; ++kc){
    int k0 = kc * 32;
    #pragma unroll
    for (int e = tid; e < 512; e += 256){
      int kk = e >> 4, pp = e & 15;
      int p = p0 + pp;
      float v = (p < P_) ? imf[((size_t)b * C_ + (k0 + kk)) * P_ + p] : 0.f;
      Bs[pp * 40 + kk] = f2b(v);
    }
    __syncthreads();
    bf16x8 bfrag = *((const bf16x8*)(Bs + l15 * 40 + quad * 8));
    #pragma unroll
    for (int m = 0; m < 4; ++m){
      int u = wv * 64 + m * 16 + l15;
      bf16x8 afrag = *((const bf16x8*)(WkeyB + (size_t)u * C_ + k0 + quad * 8));
      acc[m] = __builtin_amdgcn_mfma_f32_16x16x32_bf16(afrag, bfrag, acc[m], 0, 0, 0);
    }
    __syncthreads();
  }
  // D: u = wv*64 + m*16 + quad*4 + r, p = p0 + l15 -> pack 4 u's per store
  int p = p0 + l15;
  if (p < P_){
    #pragma unroll
    for (int m = 0; m < 4; ++m){
      ushort4 o;
      o.x = f2b(acc[m][0]); o.y = f2b(acc[m][1]);
      o.z = f2b(acc[m][2]); o.w = f2b(acc[m][3]);
      *((ushort4*)(keysT + ((size_t)b * P_ + p) * U_ + wv * 64 + m * 16 + quad * 4)) = o;
    }
  }
}

// ------- attention: scores(keysT rows) -> softmax -> attn; fill X ------
// grid (128 b, 2 halves): both halves do scores+softmax; wsum split by c.
__global__ void __launch_bounds__(256) k_attn4(
    const u16* __restrict__ imb, const u16* __restrict__ keysT,
    const float* __restrict__ qsrc, const int* __restrict__ cap,
    const float* __restrict__ emb, float* __restrict__ attn_ws,
    unsigned int* __restrict__ X, float* __restrict__ maps, int t)
{
  __shared__ __align__(16) float qs[U_];
  __shared__ __align__(16) float red[256];
  __shared__ __align__(16) float wl[256];
  int b = blockIdx.x, half = blockIdx.y, tid = threadIdx.x;
  qs[tid] = qsrc[b * U_ + tid];               // blockDim == U_ == 256
  __syncthreads();
  float s = -1e30f;
  if (tid < P_){
    const u16* kp = keysT + ((size_t)b * P_ + tid) * U_;
    float acc = 0.f;
    #pragma unroll
    for (int i = 0; i < 32; ++i){
      bf16x8 v8 = *((const bf16x8*)(kp + i * 8));
      #pragma unroll
      for (int j = 0; j < 8; ++j) acc += qs[i * 8 + j] * b2f((u16)v8[j]);
    }
    s = acc * 0.0625f;   // 1/sqrt(256)
  }
  red[tid] = s; __syncthreads();
  for (int off = 128; off > 0; off >>= 1){
    if (tid < off) red[tid] = fmaxf(red[tid], red[tid + off]);
    __syncthreads();
  }
  float mx = red[0]; __syncthreads();
  float e = (tid < P_) ? __expf(s - mx) : 0.f;
  red[tid] = e; __syncthreads();
  for (int off = 128; off > 0; off >>= 1){
    if (tid < off) red[tid] += red[tid + off];
    __syncthreads();
  }
  float inv = 1.f / red[0];
  float w = e * inv;                           // 0 for tid >= P_
  wl[tid] = w;
  if (half == 0 && tid < P_)
    maps[(size_t)(b * T_ + t) * P_ + tid] = w;
  __syncthreads();
  // weighted sum over bf16 imb rows: c = half*256 + tid
  size_t xrow = (size_t)(b * T_ + t) * KX_;
  int c = half * 256 + tid;
  {
    const u16* vrow = imb + ((size_t)b * C_ + c) * PP_;
    float a = 0.f;
    #pragma unroll
    for (int i = 0; i < 25; ++i){
      bf16x8 v8 = *((const bf16x8*)(vrow + i * 8));
      #pragma unroll
      for (int j = 0; j < 8; ++j) a += wl[i * 8 + j] * b2f((u16)v8[j]);
    }
    attn_ws[b * C_ + c] = a;
    X[xrow + c] = dup(a);
  }
  if (half == 0 && tid < E_){
    int ix = cap[b * T_ + t];
    X[xrow + C_ + tid] = dup(emb[(size_t)ix * E_ + tid]);
  }
}

// ---------------- gates GEMM (MFMA) + LSTM pointwise -------------------
// grid 128 = 8 b-tiles(16) x 16 u-tiles(16); 4 waves, wave = gate index.
__global__ void __launch_bounds__(256) k_gates(
    const float* __restrict__ Wih, const float* __restrict__ bih,
    const float* __restrict__ Whh, const float* __restrict__ bhh,
    const int* __restrict__ cap, const float* __restrict__ emb,
    const float* __restrict__ attn_ws, const float* __restrict__ hprev,
    float* __restrict__ c_st, float* __restrict__ hnew,
    unsigned int* __restrict__ X, int t)
{
  __shared__ __align__(16) u16 xg[16 * 32];
  __shared__ __align__(16) u16 wt[64 * 32];
  __shared__ __align__(16) float gl[4 * 16 * 16];
  __shared__ int ixl[16];
  int tid = threadIdx.x;
  int b0 = (blockIdx.x >> 4) * 16;
  int u0 = (blockIdx.x & 15) * 16;
  if (tid < 16) ixl[tid] = cap[(b0 + tid) * T_ + t];
  __syncthreads();
  int lane = tid & 63, wv = tid >> 6;
  int quad = lane >> 4, l15 = lane & 15;
  f32x4 acc = {0.f, 0.f, 0.f, 0.f};
  for (int kc = 0; kc < 28; ++kc){
    int k0 = kc * 32;
    // stage xg[16][32]: k<128 emb, 128..639 attn, 640..895 h  (f32 -> bf16)
    for (int e2 = tid; e2 < 512; e2 += 256){
      int r = e2 >> 5, kk = e2 & 31, k = k0 + kk;
      float v;
      if (k < 128)      v = emb[(size_t)ixl[r] * E_ + k];
      else if (k < 640) v = attn_ws[(b0 + r) * C_ + (k - 128)];
      else              v = hprev[(b0 + r) * U_ + (k - 640)];
      xg[e2] = f2b(v);
    }
    // stage wt[64][32]: rows j = g*256 + u0 + r (g=jl>>4, r=jl&15), f32->bf16
    {
      int jl = tid >> 2, seg = tid & 3;
      int g = jl >> 4, r = jl & 15;
      int j = g * 256 + u0 + r;
      const float* src = (kc < 20)
          ? (Wih + (size_t)j * 640 + k0 + seg * 8)
          : (Whh + (size_t)j * 256 + (k0 - 640) + seg * 8);
      float4 lo = ((const float4*)src)[0];
      float4 hi = ((const float4*)src)[1];
      uint4 o;
      o.x = pk2(lo.x, lo.y); o.y = pk2(lo.z, lo.w);
      o.z = pk2(hi.x, hi.y); o.w = pk2(hi.z, hi.w);
      *((uint4*)(wt + jl * 32 + seg * 8)) = o;
    }
    __syncthreads();
    bf16x8 af  = *((const bf16x8*)(xg + l15 * 32 + quad * 8));
    bf16x8 bfv = *((const bf16x8*)(wt + (wv * 16 + l15) * 32 + quad * 8));
    acc = __builtin_amdgcn_mfma_f32_16x16x32_bf16(af, bfv, acc, 0, 0, 0);
    __syncthreads();
  }
  // D: row m = quad*4+reg (b), col n = l15 (u); wave wv = gate
  #pragma unroll
  for (int r = 0; r < 4; ++r)
    gl[(wv << 8) + ((quad * 4 + r) << 4) + l15] = acc[r];
  __syncthreads();
  {
    int br = tid >> 4, ur = tid & 15;
    int b = b0 + br, u = u0 + ur;
    float i_g = gl[(0 << 8) + (br << 4) + ur] + bih[u]       + bhh[u];
    float f_g = gl[(1 << 8) + (br << 4) + ur] + bih[256 + u] + bhh[256 + u];
    float g_g = gl[(2 << 8) + (br << 4) + ur] + bih[512 + u] + bhh[512 + u];
    float o_g = gl[(3 << 8) + (br << 4) + ur] + bih[768 + u] + bhh[768 + u];
    float cold = c_st[b * U_ + u];
    float si = 1.f / (1.f + __expf(-i_g));
    float sf = 1.f / (1.f + __expf(-f_g));
    float so = 1.f / (1.f + __expf(-o_g));
    float cn = sf * cold + si * tanhf(g_g);
    float hn = so * tanhf(cn);
    c_st[b * U_ + u] = cn;
    hnew[b * U_ + u] = hn;
    X[(size_t)(b * T_ + t) * KX_ + 640 + u] = dup(hn);
  }
}

// ---------------- W_out -> hi/lo bf16 pairs, zero-padded to NPAD_ ------
__global__ void k_wsplit(const float* __restrict__ Wout,
                         unsigned int* __restrict__ W2){
  int idx = blockIdx.x * 256 + threadIdx.x;        // NPAD_*224 = 2,351,104
  int v = idx / 224, kq = idx - v * 224;
  uint4 o;
  if (v < V_){
    float4 w = ((const float4*)(Wout + (size_t)v * KX_))[kq];
    o.x = hl(w.x); o.y = hl(w.y); o.z = hl(w.z); o.w = hl(w.w);
  } else {
    o.x = o.y = o.z = o.w = 0u;
  }
  ((uint4*)(W2 + (size_t)v * KX_))[kq] = o;
}

// ---------------- logits GEMM: MFMA, m97 structure ---------------------
// C[4096, NPAD_] = A2[4096, K2_] * W2[NPAD_, K2_]^T  (bf16, K doubled)
__global__ void __launch_bounds__(256) k_logits(
    const u16* __restrict__ A2, const u16* __restrict__ W2,
    const float* __restrict__ bout, float* __restrict__ out)
{
  __shared__ __align__(16) u16 As[128 * 32];
  __shared__ __align__(16) u16 Bs[128 * 32];
  int tid = threadIdx.x;
  int n0 = blockIdx.x * 128;
  int m0 = blockIdx.y * 128;
  int lane = tid & 63, wv = tid >> 6;
  int wm = wv >> 1, wn = wv & 1;
  int quad = lane >> 4, l15 = lane & 15;

  f32x4 acc[4][4];
  #pragma unroll
  for (int i = 0; i < 4; ++i)
    #pragma unroll
    for (int j = 0; j < 4; ++j)
      acc[i][j] = (f32x4){0.f, 0.f, 0.f, 0.f};

  int rsub = tid >> 2, seg = tid & 3;
  const u16* ga0 = A2 + (size_t)(m0 + rsub)      * K2_ + seg * 8;
  const u16* ga1 = A2 + (size_t)(m0 + 64 + rsub) * K2_ + seg * 8;
  const u16* gb0 = W2 + (size_t)(n0 + rsub)      * K2_ + seg * 8;
  const u16* gb1 = W2 + (size_t)(n0 + 64 + rsub) * K2_ + seg * 8;
  u16* lA0 = As + tid * 8;
  u16* lA1 = As + (256 + tid) * 8;
  u16* lB0 = Bs + tid * 8;
  u16* lB1 = Bs + (256 + tid) * 8;

  const u16* arow0 = As + (wm * 64 + l15) * 32 + quad * 8;
  const u16* brow0 = Bs + (wn * 64 + l15) * 32 + quad * 8;

  for (int kc = 0; kc < 56; ++kc){
    __builtin_amdgcn_global_load_lds(ga0, lA0, 16, 0, 0);
    __builtin_amdgcn_global_load_lds(ga1, lA1, 16, 0, 0);
    __builtin_amdgcn_global_load_lds(gb0, lB0, 16, 0, 0);
    __builtin_amdgcn_global_load_lds(gb1, lB1, 16, 0, 0);
    ga0 += 32; ga1 += 32; gb0 += 32; gb1 += 32;
    __syncthreads();
    bf16x8 a[4], b[4];
    #pragma unroll
    for (int i = 0; i < 4; ++i)
      a[i] = *((const bf16x8*)(arow0 + i * 16 * 32));
    #pragma unroll
    for (int j = 0; j < 4; ++j)
      b[j] = *((const bf16x8*)(brow0 + j * 16 * 32));
    #pragma unroll
    for (int i = 0; i < 4; ++i)
      #pragma unroll
      for (int j = 0; j < 4; ++j)
        acc[i][j] = __builtin_amdgcn_mfma_f32_16x16x32_bf16(a[i], b[j], acc[i][j], 0, 0, 0);
    __syncthreads();
  }

  int orow = m0 + wm * 64 + quad * 4;
  #pragma unroll
  for (int j = 0; j < 4; ++j){
    int v = n0 + wn * 64 + j * 16 + l15;
    if (v < V_){
      float bo = bout[v];
      #pragma unroll
      for (int i = 0; i < 4; ++i){
        #pragma unroll
        for (int r = 0; r < 4; ++r)
          out[(size_t)(orow + i * 16 + r) * V_ + v] = acc[i][j][r] + bo;
      }
    }
  }
}

extern "C" void kernel_launch(void* const* d_in, const int* in_sizes, int n_in,
                              void* d_out, int out_size, void* d_ws, size_t ws_size,
                              hipStream_t stream)
{
  const float* imf  = (const float*)d_in[0];
  const int*   cap  = (const int*)d_in[1];
  const float* Wh0  = (const float*)d_in[2];
  const float* bh0  = (const float*)d_in[3];
  const float* Wc0  = (const float*)d_in[4];
  const float* bc0  = (const float*)d_in[5];
  const float* Wkey = (const float*)d_in[6];
  // d_in[7] = b_key: softmax-invariant (constant shift per b) -> unused
  const float* emb  = (const float*)d_in[8];
  const float* Wih  = (const float*)d_in[9];
  const float* bih  = (const float*)d_in[10];
  const float* Whh  = (const float*)d_in[11];
  const float* bhh  = (const float*)d_in[12];
  const float* Wout = (const float*)d_in[13];
  const float* bout = (const float*)d_in[14];

  // workspace layout (~93 MB)
  float* mean  = (float*)d_ws;                        // 65536 f32
  float* hbuf0 = mean  + 65536;                       // 32768
  float* hbuf1 = hbuf0 + 32768;                       // 32768
  float* cbuf  = hbuf1 + 32768;                       // 32768
  float* attn  = cbuf  + 32768;                       // 65536
  unsigned int* X  = (unsigned int*)(attn + 65536);   // 4096*896 u32 (dup bf16)
  unsigned int* W2 = X + (size_t)4096 * KX_;          // 10496*896 u32 (hi|lo)
  u16* WkeyB = (u16*)(W2 + (size_t)NPAD_ * KX_);      // 256*512 bf16
  u16* keysT = WkeyB + 131072;                        // 128*196*256 bf16 [b][p][u]
  u16* imb   = keysT + (size_t)B_ * P_ * U_;          // 128*512*200 bf16

  float* out  = (float*)d_out;
  float* maps = out + (size_t)B_ * T_ * V_;

  k_wsplit<<<9184, 256, 0, stream>>>(Wout, W2);
  k_wkeyb<<<512, 256, 0, stream>>>(Wkey, WkeyB);
  k_prep<<<256, 256, 0, stream>>>(imf, mean, imb);
  k_keys<<<dim3(13, 128), 256, 0, stream>>>(imf, WkeyB, keysT);
  k_h0c0<<<256, 256, 0, stream>>>(mean, Wh0, bh0, Wc0, bc0, hbuf0, cbuf);
  for (int t = 0; t < T_; ++t){
    const float* q  = (t == 0) ? cbuf : ((t & 1) ? hbuf1 : hbuf0);
    const float* hp = (t & 1) ? hbuf1 : hbuf0;
    float*       hn = (t & 1) ? hbuf0 : hbuf1;
    k_attn4<<<dim3(128, 2), 256, 0, stream>>>(imb, keysT, q, cap, emb, attn,
                                              X, maps, t);
    k_gates<<<128, 256, 0, stream>>>(Wih, bih, Whh, bhh, cap, emb, attn,
                                     hp, cbuf, hn, X, t);
  }
  k_logits<<<dim3(82, 32), 256, 0, stream>>>((const u16*)X, (const u16*)W2,
                                             bout, out);
}

// Round 8
// 1550.272 us; speedup vs baseline: 2.4550x; 1.4391x over previous
//
#include <hip/hip_runtime.h>
#include <stdint.h>

// Problem constants
#define B_   128
#define C_   512
#define P_   196
#define PP_  200     // padded P for bf16 image features rows
#define T_   32
#define V_   10403
#define E_   128
#define U_   256
#define KX_  896     // C+E+U : X row width in PAIRED u32 units (attn|emb|h)
#define K2_  1792    // doubled K for hi/lo split GEMM
#define NPAD_ 10496  // 82 * 128, padded N for the logits GEMM
#define WLD_ 904     // padded LDS row stride (bf16 elems) for gates tiles

typedef unsigned short u16;
typedef __attribute__((ext_vector_type(8))) short bf16x8;
typedef __attribute__((ext_vector_type(4))) float f32x4;

__device__ __forceinline__ float b2f(u16 u){
  union { unsigned int i; float f; } v; v.i = ((unsigned int)u) << 16; return v.f;
}
__device__ __forceinline__ u16 f2b(float f){
  union { float f; unsigned int i; } v; v.f = f;
  unsigned int r = (v.i + 0x7FFFu + ((v.i >> 16) & 1u)) >> 16;
  return (u16)r;
}
// duplicate one bf16 value into both halves of a u32 (K-doubled X element)
__device__ __forceinline__ unsigned int dup(float a){
  return (unsigned int)f2b(a) * 0x00010001u;
}
// hi/lo split of fp32 weight into two bf16 halves packed in one u32
__device__ __forceinline__ unsigned int hl(float w){
  u16 h = f2b(w);
  float lo = w - b2f(h);
  return (unsigned int)h | ((unsigned int)f2b(lo) << 16);
}

// ------------- prep: mean over P + bf16 image features [b][c][200] -----
__global__ void k_prep(const float* __restrict__ imf, float* __restrict__ mean,
                       u16* __restrict__ imb){
  int idx = blockIdx.x * 256 + threadIdx.x;          // b*C + c, 65536 total
  const float4* p4 = (const float4*)(imf + (size_t)idx * P_);
  u16* orow = imb + (size_t)idx * PP_;
  float s = 0.f;
  for (int i = 0; i < 49; ++i){
    float4 q = p4[i];
    s += q.x + q.y + q.z + q.w;
    ushort4 o;
    o.x = f2b(q.x); o.y = f2b(q.y); o.z = f2b(q.z); o.w = f2b(q.w);
    *((ushort4*)(orow + 4 * i)) = o;
  }
  ushort4 z; z.x = z.y = z.z = z.w = 0;
  *((ushort4*)(orow + 196)) = z;
  mean[idx] = s * (1.f / 196.f);
}

// ------- h0 = mean@W_h0^T + b_h0 ; c0 = mean@W_c0^T + b_c0 (+dup h0) ---
__global__ void k_h0c0(const float* __restrict__ mean,
                       const float* __restrict__ Wh, const float* __restrict__ bh,
                       const float* __restrict__ Wc, const float* __restrict__ bc,
                       float* __restrict__ h0, float* __restrict__ c0,
                       unsigned int* __restrict__ h0b){
  int idx = blockIdx.x * 256 + threadIdx.x;          // b*512 + j
  int b = idx >> 9, j = idx & 511;
  int u = j & 255, isc = j >> 8;
  const float* wr = (isc ? Wc : Wh) + (size_t)u * C_;
  const float* m = mean + b * C_;
  float s = 0.f;
  for (int c = 0; c < C_; ++c) s += m[c] * wr[c];
  s += (isc ? bc : bh)[u];
  (isc ? c0 : h0)[b * U_ + u] = s;
  if (!isc) h0b[b * U_ + u] = dup(s);
}

// ---------------- Wkey f32 -> bf16 -----------------------------------
__global__ void k_wkeyb(const float* __restrict__ Wk, u16* __restrict__ WkB){
  int idx = blockIdx.x * 256 + threadIdx.x;          // 256*512 = 131072
  WkB[idx] = f2b(Wk[idx]);
}

// ------- gate weights -> bf16, columns reordered to attn|emb|h ---------
__global__ void k_wgb(const float* __restrict__ Wih, const float* __restrict__ Whh,
                      u16* __restrict__ Wg){
  int idx = blockIdx.x * 256 + threadIdx.x;          // 1024*896
  int j = idx / 896, k = idx - j * 896;
  float w;
  if (k < 512)      w = Wih[(size_t)j * 640 + 128 + k];   // attn part
  else if (k < 640) w = Wih[(size_t)j * 640 + (k - 512)]; // emb part
  else              w = Whh[(size_t)j * 256 + (k - 640)]; // h part
  Wg[(size_t)j * 896 + k] = f2b(w);
}

// ---------------- X emb columns for all (b,t): t-independent -----------
__global__ void k_xemb(const int* __restrict__ cap, const float* __restrict__ emb,
                       unsigned int* __restrict__ X){
  int idx = blockIdx.x * 256 + threadIdx.x;          // row*128 + e, 4096*128
  int row = idx >> 7, e = idx & 127;
  int ix = cap[row];                                 // row = b*T + t
  X[(size_t)row * KX_ + C_ + e] = dup(emb[(size_t)ix * E_ + e]);
}

// ---------------- keysT[b,p,u] = sum_c Wkey[u,c] * imf[b,c,p] ----------
// one-time MFMA GEMM, bf16 out, u-contiguous rows. grid (13 p-tiles x 128 b).
__global__ void __launch_bounds__(256) k_keys(
    const float* __restrict__ imf, const u16* __restrict__ WkeyB,
    u16* __restrict__ keysT)
{
  __shared__ __align__(16) u16 Bs[16 * 40];   // [p][k], stride 40 breaks conflicts
  int tid = threadIdx.x;
  int p0 = blockIdx.x * 16;                   // 0..192
  int b  = blockIdx.y;
  int lane = tid & 63, wv = tid >> 6;
  int quad = lane >> 4, l15 = lane & 15;
  f32x4 acc[4];
  #pragma unroll
  for (int m = 0; m < 4; ++m) acc[m] = (f32x4){0.f, 0.f, 0.f, 0.f};
  for (int kc = 0; kc < 16; ++kc){
    int k0 = kc * 32;
    #pragma unroll
    for (int e = tid; e < 512; e += 256){
      int kk = e >> 4, pp = e & 15;
      int p = p0 + pp;
      float v = (p < P_) ? imf[((size_t)b * C_ + (k0 + kk)) * P_ + p] : 0.f;
      Bs[pp * 40 + kk] = f2b(v);
    }
    __syncthreads();
    bf16x8 bfrag = *((const bf16x8*)(Bs + l15 * 40 + quad * 8));
    #pragma unroll
    for (int m = 0; m < 4; ++m){
      int u = wv * 64 + m * 16 + l15;
      bf16x8 afrag = *((const bf16x8*)(WkeyB + (size_t)u * C_ + k0 + quad * 8));
      acc[m] = __builtin_amdgcn_mfma_f32_16x16x32_bf16(afrag, bfrag, acc[m], 0, 0, 0);
    }
    __syncthreads();
  }
  int p = p0 + l15;
  if (p < P_){
    #pragma unroll
    for (int m = 0; m < 4; ++m){
      ushort4 o;
      o.x = f2b(acc[m][0]); o.y = f2b(acc[m][1]);
      o.z = f2b(acc[m][2]); o.w = f2b(acc[m][3]);
      *((ushort4*)(keysT + ((size_t)b * P_ + p) * U_ + wv * 64 + m * 16 + quad * 4)) = o;
    }
  }
}

// ------- attention: scores(keysT rows) -> softmax -> attn; fill X ------
// grid (128 b, 2 halves): both halves do scores+softmax; wsum split by c.
__global__ void __launch_bounds__(256) k_attn4(
    const u16* __restrict__ imb, const u16* __restrict__ keysT,
    const float* __restrict__ qsrc, const int* __restrict__ cap,
    const float* __restrict__ emb, unsigned int* __restrict__ X,
    float* __restrict__ maps, int t)
{
  __shared__ __align__(16) float qs[U_];
  __shared__ __align__(16) float red[256];
  __shared__ __align__(16) float wl[256];
  int b = blockIdx.x, half = blockIdx.y, tid = threadIdx.x;
  qs[tid] = qsrc[b * U_ + tid];               // blockDim == U_ == 256
  __syncthreads();
  float s = -1e30f;
  if (tid < P_){
    const u16* kp = keysT + ((size_t)b * P_ + tid) * U_;
    float acc = 0.f;
    #pragma unroll
    for (int i = 0; i < 32; ++i){
      bf16x8 v8 = *((const bf16x8*)(kp + i * 8));
      #pragma unroll
      for (int j = 0; j < 8; ++j) acc += qs[i * 8 + j] * b2f((u16)v8[j]);
    }
    s = acc * 0.0625f;   // 1/sqrt(256)
  }
  red[tid] = s; __syncthreads();
  for (int off = 128; off > 0; off >>= 1){
    if (tid < off) red[tid] = fmaxf(red[tid], red[tid + off]);
    __syncthreads();
  }
  float mx = red[0]; __syncthreads();
  float e = (tid < P_) ? __expf(s - mx) : 0.f;
  red[tid] = e; __syncthreads();
  for (int off = 128; off > 0; off >>= 1){
    if (tid < off) red[tid] += red[tid + off];
    __syncthreads();
  }
  float inv = 1.f / red[0];
  float w = e * inv;                           // 0 for tid >= P_
  wl[tid] = w;
  if (half == 0 && tid < P_)
    maps[(size_t)(b * T_ + t) * P_ + tid] = w;
  __syncthreads();
  // weighted sum over bf16 imb rows: c = half*256 + tid
  size_t xrow = (size_t)(b * T_ + t) * KX_;
  int c = half * 256 + tid;
  {
    const u16* vrow = imb + ((size_t)b * C_ + c) * PP_;
    float a = 0.f;
    #pragma unroll
    for (int i = 0; i < 25; ++i){
      bf16x8 v8 = *((const bf16x8*)(vrow + i * 8));
      #pragma unroll
      for (int j = 0; j < 8; ++j) a += wl[i * 8 + j] * b2f((u16)v8[j]);
    }
    X[xrow + c] = dup(a);
  }
  if (half == 0 && tid < E_){
    int ix = cap[b * T_ + t];
    X[xrow + C_ + tid] = dup(emb[(size_t)ix * E_ + tid]);
  }
}

// ------- gates GEMM v3: whole W-tile + X-tile LDS-resident -------------
// grid 128 = 8 b-tiles(16) x 16 u-tiles(16); 4 waves, wave = gate index.
// Stage once (no per-k barriers), then 28 MFMA from LDS.
// A source: X rows (dup-packed bf16): attn/emb from row t, h from row t-1
// (h0b at t=0). B source: Wg (bf16, attn|emb|h column order).
__global__ void __launch_bounds__(256) k_gates3(
    const u16* __restrict__ Wg, const float* __restrict__ bih,
    const float* __restrict__ bhh, const unsigned int* __restrict__ h0b,
    float* __restrict__ c_st, float* __restrict__ hnew,
    unsigned int* X, int t)
{
  __shared__ __align__(16) u16 wls[64 * WLD_];   // 115,712 B
  __shared__ __align__(16) u16 xls[16 * WLD_];   //  28,928 B
  __shared__ __align__(16) float gl[4 * 16 * 16];
  int tid = threadIdx.x;
  int b0 = (blockIdx.x >> 4) * 16;
  int u0 = (blockIdx.x & 15) * 16;
  // ---- stage X-rows tile: 16 rows x 224 u32-quads (dup -> low bf16) ----
  for (int e = tid; e < 16 * 224; e += 256){
    int r = e / 224, q4 = e - r * 224;
    const unsigned int* src;
    if (q4 < 160)       src = X + ((size_t)((b0 + r) * T_ + t)) * KX_ + q4 * 4;
    else if (t > 0)     src = X + ((size_t)((b0 + r) * T_ + t - 1)) * KX_ + q4 * 4;
    else                src = h0b + (b0 + r) * U_ + (q4 * 4 - 640);
    uint4 v = *((const uint4*)src);
    ushort4 o;
    o.x = (u16)v.x; o.y = (u16)v.y; o.z = (u16)v.z; o.w = (u16)v.w;
    *((ushort4*)(xls + r * WLD_ + q4 * 4)) = o;
  }
  // ---- stage W tile: 64 rows (4 gates x 16 u) x 112 8-elem chunks ------
  for (int e = tid; e < 64 * 112; e += 256){
    int jl = e / 112, s8 = e - jl * 112;
    int j = ((jl >> 4) << 8) + u0 + (jl & 15);
    uint4 v = *((const uint4*)(Wg + (size_t)j * 896 + s8 * 8));
    *((uint4*)(wls + jl * WLD_ + s8 * 8)) = v;
  }
  __syncthreads();
  // ---- barrier-free K loop: 28 x (2 ds_read_b128 + MFMA) ---------------
  int lane = tid & 63, wv = tid >> 6;
  int quad = lane >> 4, l15 = lane & 15;
  f32x4 acc = {0.f, 0.f, 0.f, 0.f};
  #pragma unroll
  for (int kc = 0; kc < 28; ++kc){
    bf16x8 af  = *((const bf16x8*)(xls + l15 * WLD_ + kc * 32 + quad * 8));
    bf16x8 bfv = *((const bf16x8*)(wls + (wv * 16 + l15) * WLD_ + kc * 32 + quad * 8));
    acc = __builtin_amdgcn_mfma_f32_16x16x32_bf16(af, bfv, acc, 0, 0, 0);
  }
  // ---- epilogue: D row m = quad*4+reg (b), col n = l15 (u); wv = gate --
  #pragma unroll
  for (int r = 0; r < 4; ++r)
    gl[(wv << 8) + ((quad * 4 + r) << 4) + l15] = acc[r];
  __syncthreads();
  {
    int br = tid >> 4, ur = tid & 15;
    int b = b0 + br, u = u0 + ur;
    float i_g = gl[(0 << 8) + (br << 4) + ur] + bih[u]       + bhh[u];
    float f_g = gl[(1 << 8) + (br << 4) + ur] + bih[256 + u] + bhh[256 + u];
    float g_g = gl[(2 << 8) + (br << 4) + ur] + bih[512 + u] + bhh[512 + u];
    float o_g = gl[(3 << 8) + (br << 4) + ur] + bih[768 + u] + bhh[768 + u];
    float cold = c_st[b * U_ + u];
    float si = 1.f / (1.f + __expf(-i_g));
    float sf = 1.f / (1.f + __expf(-f_g));
    float so = 1.f / (1.f + __expf(-o_g));
    float cn = sf * cold + si * tanhf(g_g);
    float hn = so * tanhf(cn);
    c_st[b * U_ + u] = cn;
    hnew[b * U_ + u] = hn;
    X[(size_t)(b * T_ + t) * KX_ + 640 + u] = dup(hn);
  }
}

// ---------------- W_out -> hi/lo bf16 pairs, zero-padded to NPAD_ ------
__global__ void k_wsplit(const float* __restrict__ Wout,
                         unsigned int* __restrict__ W2){
  int idx = blockIdx.x * 256 + threadIdx.x;        // NPAD_*224 = 2,351,104
  int v = idx / 224, kq = idx - v * 224;
  uint4 o;
  if (v < V_){
    float4 w = ((const float4*)(Wout + (size_t)v * KX_))[kq];
    o.x = hl(w.x); o.y = hl(w.y); o.z = hl(w.z); o.w = hl(w.w);
  } else {
    o.x = o.y = o.z = o.w = 0u;
  }
  ((uint4*)(W2 + (size_t)v * KX_))[kq] = o;
}

// ---------------- logits GEMM: MFMA, m97 structure ---------------------
// C[4096, NPAD_] = A2[4096, K2_] * W2[NPAD_, K2_]^T  (bf16, K doubled)
__global__ void __launch_bounds__(256) k_logits(
    const u16* __restrict__ A2, const u16* __restrict__ W2,
    const float* __restrict__ bout, float* __restrict__ out)
{
  __shared__ __align__(16) u16 As[128 * 32];
  __shared__ __align__(16) u16 Bs[128 * 32];
  int tid = threadIdx.x;
  int n0 = blockIdx.x * 128;
  int m0 = blockIdx.y * 128;
  int lane = tid & 63, wv = tid >> 6;
  int wm = wv >> 1, wn = wv & 1;
  int quad = lane >> 4, l15 = lane & 15;

  f32x4 acc[4][4];
  #pragma unroll
  for (int i = 0; i < 4; ++i)
    #pragma unroll
    for (int j = 0; j < 4; ++j)
      acc[i][j] = (f32x4){0.f, 0.f, 0.f, 0.f};

  int rsub = tid >> 2, seg = tid & 3;
  const u16* ga0 = A2 + (size_t)(m0 + rsub)      * K2_ + seg * 8;
  const u16* ga1 = A2 + (size_t)(m0 + 64 + rsub) * K2_ + seg * 8;
  const u16* gb0 = W2 + (size_t)(n0 + rsub)      * K2_ + seg * 8;
  const u16* gb1 = W2 + (size_t)(n0 + 64 + rsub) * K2_ + seg * 8;
  u16* lA0 = As + tid * 8;
  u16* lA1 = As + (256 + tid) * 8;
  u16* lB0 = Bs + tid * 8;
  u16* lB1 = Bs + (256 + tid) * 8;

  const u16* arow0 = As + (wm * 64 + l15) * 32 + quad * 8;
  const u16* brow0 = Bs + (wn * 64 + l15) * 32 + quad * 8;

  for (int kc = 0; kc < 56; ++kc){
    __builtin_amdgcn_global_load_lds(ga0, lA0, 16, 0, 0);
    __builtin_amdgcn_global_load_lds(ga1, lA1, 16, 0, 0);
    __builtin_amdgcn_global_load_lds(gb0, lB0, 16, 0, 0);
    __builtin_amdgcn_global_load_lds(gb1, lB1, 16, 0, 0);
    ga0 += 32; ga1 += 32; gb0 += 32; gb1 += 32;
    __syncthreads();
    bf16x8 a[4], b[4];
    #pragma unroll
    for (int i = 0; i < 4; ++i)
      a[i] = *((const bf16x8*)(arow0 + i * 16 * 32));
    #pragma unroll
    for (int j = 0; j < 4; ++j)
      b[j] = *((const bf16x8*)(brow0 + j * 16 * 32));
    #pragma unroll
    for (int i = 0; i < 4; ++i)
      #pragma unroll
      for (int j = 0; j < 4; ++j)
        acc[i][j] = __builtin_amdgcn_mfma_f32_16x16x32_bf16(a[i], b[j], acc[i][j], 0, 0, 0);
    __syncthreads();
  }

  int orow = m0 + wm * 64 + quad * 4;
  #pragma unroll
  for (int j = 0; j < 4; ++j){
    int v = n0 + wn * 64 + j * 16 + l15;
    if (v < V_){
      float bo = bout[v];
      #pragma unroll
      for (int i = 0; i < 4; ++i){
        #pragma unroll
        for (int r = 0; r < 4; ++r)
          out[(size_t)(orow + i * 16 + r) * V_ + v] = acc[i][j][r] + bo;
      }
    }
  }
}

extern "C" void kernel_launch(void* const* d_in, const int* in_sizes, int n_in,
                              void* d_out, int out_size, void* d_ws, size_t ws_size,
                              hipStream_t stream)
{
  const float* imf  = (const float*)d_in[0];
  const int*   cap  = (const int*)d_in[1];
  const float* Wh0  = (const float*)d_in[2];
  const float* bh0  = (const float*)d_in[3];
  const float* Wc0  = (const float*)d_in[4];
  const float* bc0  = (const float*)d_in[5];
  const float* Wkey = (const float*)d_in[6];
  // d_in[7] = b_key: softmax-invariant (constant shift per b) -> unused
  const float* emb  = (const float*)d_in[8];
  const float* Wih  = (const float*)d_in[9];
  const float* bih  = (const float*)d_in[10];
  const float* Whh  = (const float*)d_in[11];
  const float* bhh  = (const float*)d_in[12];
  const float* Wout = (const float*)d_in[13];
  const float* bout = (const float*)d_in[14];

  // workspace layout (~94 MB)
  float* mean  = (float*)d_ws;                        // 65536 f32
  float* hbuf0 = mean  + 65536;                       // 32768
  float* hbuf1 = hbuf0 + 32768;                       // 32768
  float* cbuf  = hbuf1 + 32768;                       // 32768
  unsigned int* h0b = (unsigned int*)(cbuf + 32768);  // 32768 u32 (dup h0)
  unsigned int* X   = h0b + 32768;                    // 4096*896 u32 (dup bf16)
  unsigned int* W2  = X + (size_t)4096 * KX_;         // 10496*896 u32 (hi|lo)
  u16* Wg    = (u16*)(W2 + (size_t)NPAD_ * KX_);      // 1024*896 bf16 (reordered)
  u16* WkeyB = Wg + (size_t)1024 * 896;               // 256*512 bf16
  u16* keysT = WkeyB + 131072;                        // 128*196*256 bf16 [b][p][u]
  u16* imb   = keysT + (size_t)B_ * P_ * U_;          // 128*512*200 bf16

  float* out  = (float*)d_out;
  float* maps = out + (size_t)B_ * T_ * V_;

  k_wsplit<<<9184, 256, 0, stream>>>(Wout, W2);
  k_wgb<<<3584, 256, 0, stream>>>(Wih, Whh, Wg);
  k_wkeyb<<<512, 256, 0, stream>>>(Wkey, WkeyB);
  k_prep<<<256, 256, 0, stream>>>(imf, mean, imb);
  k_keys<<<dim3(13, 128), 256, 0, stream>>>(imf, WkeyB, keysT);
  k_h0c0<<<256, 256, 0, stream>>>(mean, Wh0, bh0, Wc0, bc0, hbuf0, cbuf, h0b);
  k_xemb<<<2048, 256, 0, stream>>>(cap, emb, X);
  for (int t = 0; t < T_; ++t){
    const float* q  = (t == 0) ? cbuf : ((t & 1) ? hbuf1 : hbuf0);
    float*       hn = (t & 1) ? hbuf0 : hbuf1;
    k_attn4<<<dim3(128, 2), 256, 0, stream>>>(imb, keysT, q, cap, emb,
                                              X, maps, t);
    k_gates3<<<128, 256, 0, stream>>>(Wg, bih, bhh, h0b, cbuf, hn, X, t);
  }
  k_logits<<<dim3(82, 32), 256, 0, stream>>>((const u16*)X, (const u16*)W2,
                                             bout, out);
}